// Round 1
// 412.009 us; speedup vs baseline: 1.0068x; 1.0068x over previous
//
#include <hip/hip_runtime.h>

// out[r,2j]   = cos(q[2j]) * cos(pi * x[r,2j])
// out[r,2j+1] = out[r,2j]  * cos(q[2j+1] + pi * x[r,2j+1])
//
// Row = 16 floats = 4 float4s; float4 #c within a row covers pairs j=2c,2c+1,
// and q viewed as float4[4] gives (qe0, qo0, qe1, qo1) at index c directly.
//
// Streaming kernel, memory-bound: floor = 512 MiB @ ~6.3 TB/s ~= 85 us.
// Each block handles 512 float4s as two contiguous 256-wide tiles so both
// per-thread loads are wave-contiguous (1 KiB per wave per load instr).
// Nontemporal (nt) load/store: zero reuse, don't pollute L2/LLC.

typedef float f4 __attribute__((ext_vector_type(4)));

__global__ __launch_bounds__(256) void qconv_kernel(
    const f4* __restrict__ x, const float* __restrict__ q,
    f4* __restrict__ out, int n4) {
    const float PI = 3.14159265358979323846f;

    const int i0 = blockIdx.x * 512 + threadIdx.x;   // tile 0
    const int i1 = i0 + 256;                          // tile 1

    const bool p0 = i0 < n4;
    const bool p1 = i1 < n4;

    f4 v0 = {0.f, 0.f, 0.f, 0.f};
    f4 v1 = {0.f, 0.f, 0.f, 0.f};
    if (p0) v0 = __builtin_nontemporal_load(x + i0);
    if (p1) v1 = __builtin_nontemporal_load(x + i1);

    // (i0 + 256) & 3 == i0 & 3, so one q vector serves both elements.
    const f4 q4 = reinterpret_cast<const f4*>(q)[i0 & 3];  // (qe0,qo0,qe1,qo1)

    const float cqe0 = __cosf(q4.x);
    const float cqe1 = __cosf(q4.z);

    f4 r0, r1;
    r0.x = cqe0 * __cosf(PI * v0.x);
    r0.y = r0.x * __cosf(q4.y + PI * v0.y);
    r0.z = cqe1 * __cosf(PI * v0.z);
    r0.w = r0.z * __cosf(q4.w + PI * v0.w);

    r1.x = cqe0 * __cosf(PI * v1.x);
    r1.y = r1.x * __cosf(q4.y + PI * v1.y);
    r1.z = cqe1 * __cosf(PI * v1.z);
    r1.w = r1.z * __cosf(q4.w + PI * v1.w);

    if (p0) __builtin_nontemporal_store(r0, out + i0);
    if (p1) __builtin_nontemporal_store(r1, out + i1);
}

extern "C" void kernel_launch(void* const* d_in, const int* in_sizes, int n_in,
                              void* d_out, int out_size, void* d_ws, size_t ws_size,
                              hipStream_t stream) {
    const f4* x = (const f4*)d_in[0];
    const float* q = (const float*)d_in[1];
    f4* out = (f4*)d_out;

    int n = in_sizes[0];       // B * 16 = 67108864 floats
    int n4 = n / 4;            // 16777216 float4s

    const int block = 256;
    int grid = (n4 + 511) / 512;   // 512 float4s per block
    qconv_kernel<<<grid, block, 0, stream>>>(x, q, out, n4);
}